// Round 8
// baseline (79.353 us; speedup 1.0000x reference)
//
#include <hip/hip_runtime.h>

#define NQ   4096
#define NGRP 256
#define LL   64
#define DD   512

typedef __attribute__((ext_vector_type(8))) short short8v;
typedef __attribute__((ext_vector_type(4))) float f32x4;
typedef __attribute__((ext_vector_type(4))) unsigned short us4v;

#define SCALE 0.044194173824159216f

// float -> bf16 bits, round-to-nearest-even
static __device__ __forceinline__ unsigned short f2bf(float f) {
  union { float f; unsigned u; } x{f};
  unsigned r = x.u + 0x7fffu + ((x.u >> 16) & 1u);
  return (unsigned short)(r >> 16);
}
static __device__ __forceinline__ float bf2f(unsigned short h) {
  union { unsigned u; float f; } x{(unsigned)h << 16};
  return x.f;
}

// split fp32 float4 -> hi/lo bf16 into XOR-slot-swizzled LDS tile [rows][8 slots of us8]
static __device__ __forceinline__ void split_store(
    unsigned short* Hh, unsigned short* Hl, int r, int c4, float4 v) {
  int s = c4 >> 1, hf = c4 & 1;
  int base = (r * 8 + (s ^ (r & 7))) * 8 + hf * 4;
  unsigned short h0 = f2bf(v.x), h1 = f2bf(v.y), h2 = f2bf(v.z), h3 = f2bf(v.w);
  us4v hv = {h0, h1, h2, h3};
  us4v lv = {f2bf(v.x - bf2f(h0)), f2bf(v.y - bf2f(h1)),
             f2bf(v.z - bf2f(h2)), f2bf(v.w - bf2f(h3))};
  *(us4v*)(Hh + base) = hv;
  *(us4v*)(Hl + base) = lv;
}

// MFMA fragment load from swizzled LDS tile
static __device__ __forceinline__ short8v frag(const unsigned short* P, int r, int sl) {
  return *(const short8v*)(P + (r * 8 + (sl ^ (r & 7))) * 8);
}

// ---------------- merged prep ----------------
// blocks [0,512): W2T = Wk @ Wq^T (3-term split MFMA, SINGLE-bf16 output),
//                 BM=BN=32 -> 2 blocks/CU for short latency chain.
// blocks [512,2560): q fp32 -> bf16;  2560: starts;  2561-2562: b2 = Wk @ bq
__global__ __launch_bounds__(256) void k_prep(
    const float* __restrict__ q_in, const int* __restrict__ gid,
    const float* __restrict__ Wk, const float* __restrict__ Wq,
    const float* __restrict__ bq,
    unsigned short* __restrict__ qbf, int* __restrict__ starts,
    float* __restrict__ b2, unsigned short* __restrict__ w2t) {
  __shared__ __align__(16) unsigned short lds[4 * 32 * 64];  // 16 KB
  int b = blockIdx.x, t = threadIdx.x;
  if (b < 512) {
    unsigned short* Ah = lds;
    unsigned short* Al = lds + 2048;
    unsigned short* Bh = lds + 4096;
    unsigned short* Bl = lds + 6144;
    int lane = t & 63, wid = t >> 6;
    int wm = wid >> 1, wn = wid & 1;
    int m0 = (b >> 5) * 32;        // Wk rows (512/32 = 16)
    int n0 = (b & 31) * 32;        // Wq rows (1024/32 = 32)
    f32x4 acc = (f32x4){0.f, 0.f, 0.f, 0.f};

    for (int k0 = 0; k0 < 512; k0 += 64) {
      __syncthreads();
      #pragma unroll
      for (int i = 0; i < 2; ++i) {
        int idx = i * 256 + t, r = idx >> 4, c4 = idx & 15;
        float4 vA = *(const float4*)&Wk[(size_t)(m0 + r) * 512 + k0 + c4 * 4];
        split_store(Ah, Al, r, c4, vA);
        float4 vB = *(const float4*)&Wq[(size_t)(n0 + r) * 512 + k0 + c4 * 4];
        split_store(Bh, Bl, r, c4, vB);
      }
      __syncthreads();
      #pragma unroll
      for (int kk = 0; kk < 2; ++kk) {
        int sl = kk * 4 + (lane >> 4);
        int rA = wm * 16 + (lane & 15);
        int rB = wn * 16 + (lane & 15);
        short8v aH = frag(Ah, rA, sl), aL = frag(Al, rA, sl);
        short8v bH = frag(Bh, rB, sl), bL = frag(Bl, rB, sl);
        acc = __builtin_amdgcn_mfma_f32_16x16x32_bf16(aH, bH, acc, 0, 0, 0);
        acc = __builtin_amdgcn_mfma_f32_16x16x32_bf16(aH, bL, acc, 0, 0, 0);
        acc = __builtin_amdgcn_mfma_f32_16x16x32_bf16(aL, bH, acc, 0, 0, 0);
      }
    }
    int cn = lane & 15, rq = lane >> 4;
    #pragma unroll
    for (int j = 0; j < 4; ++j) {
      int m = m0 + wm * 16 + rq * 4 + j;
      int n = n0 + wn * 16 + cn;
      w2t[(size_t)m * 1024 + n] = f2bf(acc[j]);
    }
  } else if (b < 2560) {
    int idx = (b - 512) * 256 + t;   // one uint4 (8 bf16) per thread
    const float* src = q_in + (size_t)idx * 8;
    float4 f0 = *(const float4*)src;
    float4 f1 = *(const float4*)(src + 4);
    uint4 pk;
    pk.x = (unsigned)f2bf(f0.x) | ((unsigned)f2bf(f0.y) << 16);
    pk.y = (unsigned)f2bf(f0.z) | ((unsigned)f2bf(f0.w) << 16);
    pk.z = (unsigned)f2bf(f1.x) | ((unsigned)f2bf(f1.y) << 16);
    pk.w = (unsigned)f2bf(f1.z) | ((unsigned)f2bf(f1.w) << 16);
    ((uint4*)qbf)[idx] = pk;
  } else if (b == 2560) {
    for (int g = t; g <= NGRP; g += 256) {
      int lo = 0, hi = NQ;
      while (lo < hi) { int mid = (lo + hi) >> 1; if (gid[mid] < g) lo = mid + 1; else hi = mid; }
      starts[g] = lo;
    }
  } else {
    int dd = (b - 2561) * 256 + t;
    if (dd < DD) {
      float s = 0.f;
      const float* row = Wk + (size_t)dd * DD;
      for (int j = 0; j < DD; j += 4) {
        float4 w = *(const float4*)&row[j];
        float4 bb = *(const float4*)&bq[j];
        s += w.x*bb.x + w.y*bb.y + w.z*bb.z + w.w*bb.w;
      }
      b2[dd] = s;
    }
  }
}

// ---------------- qt = q @ W2 + b2 via 1-term bf16 MFMA ----------------
// A = qbf [4096][1024], B = w2t [512][1024] (single bf16). Output single bf16.
__global__ __launch_bounds__(256) void gemm_qt_mfma(
    const unsigned short* __restrict__ qbf,
    const unsigned short* __restrict__ w2t,
    const float* __restrict__ b2,
    unsigned short* __restrict__ qt) {
  __shared__ __align__(16) unsigned short As[64 * 64];   // 8 KB
  __shared__ __align__(16) unsigned short Bs[64 * 64];   // 8 KB
  int t = threadIdx.x;
  int lane = t & 63, wid = t >> 6;
  int wm = wid >> 1, wn = wid & 1;
  int n0 = blockIdx.x * 64, m0 = blockIdx.y * 64;

  f32x4 acc[2][2];
  #pragma unroll
  for (int i = 0; i < 2; ++i)
    #pragma unroll
    for (int j = 0; j < 2; ++j) acc[i][j] = (f32x4){0.f, 0.f, 0.f, 0.f};

  for (int k0 = 0; k0 < 1024; k0 += 64) {
    __syncthreads();
    #pragma unroll
    for (int i = 0; i < 2; ++i) {
      int idx = i * 256 + t;
      int r = idx >> 3, s = idx & 7;
      int dst = r * 8 + (s ^ (r & 7));
      ((uint4*)As)[dst] = *(const uint4*)(qbf + (size_t)(m0 + r) * 1024 + k0 + s * 8);
      ((uint4*)Bs)[dst] = *(const uint4*)(w2t + (size_t)(n0 + r) * 1024 + k0 + s * 8);
    }
    __syncthreads();
    #pragma unroll
    for (int kk = 0; kk < 2; ++kk) {
      short8v aF[2], bF[2];
      int sl = kk * 4 + (lane >> 4);
      #pragma unroll
      for (int fm = 0; fm < 2; ++fm)
        aF[fm] = frag(As, wm * 32 + fm * 16 + (lane & 15), sl);
      #pragma unroll
      for (int fn = 0; fn < 2; ++fn)
        bF[fn] = frag(Bs, wn * 32 + fn * 16 + (lane & 15), sl);
      #pragma unroll
      for (int fm = 0; fm < 2; ++fm)
        #pragma unroll
        for (int fn = 0; fn < 2; ++fn)
          acc[fm][fn] = __builtin_amdgcn_mfma_f32_16x16x32_bf16(aF[fm], bF[fn], acc[fm][fn], 0, 0, 0);
    }
  }
  int cn = lane & 15, rq = lane >> 4;
  #pragma unroll
  for (int fn = 0; fn < 2; ++fn) {
    int n = n0 + wn * 32 + fn * 16 + cn;
    float bias = b2[n];
    #pragma unroll
    for (int fm = 0; fm < 2; ++fm)
      #pragma unroll
      for (int j = 0; j < 4; ++j) {
        int m = m0 + wm * 32 + fm * 16 + rq * 4 + j;
        qt[(size_t)m * 512 + n] = f2bf(acc[fm][fn][j] + bias);
      }
  }
}

// ---------------- partial scores: S_part[dq][n][l] ----------------
// Grid 1024: g = bx>>2, dq = bx&3. 256 threads = 4 waves, wave wl owns l-tile.
// K split 2-term (exact in K); Q single bf16.
__global__ __launch_bounds__(256) void k_scores4(
    const unsigned short* __restrict__ qt,
    const float* __restrict__ kk_, const int* __restrict__ starts,
    float* __restrict__ s_part) {
  int g = blockIdx.x >> 2, dq = blockIdx.x & 3;
  int t = threadIdx.x, lane = t & 63, wl = t >> 6;
  int s0 = starts[g], s1 = starts[g + 1];
  if (s0 >= s1) return;

  __shared__ __align__(16) unsigned short Kh[64*64], Kl[64*64];  // 8 KB each
  __shared__ __align__(16) unsigned short Qs[32*64];             // 4 KB

  float* sp = s_part + (size_t)dq * NQ * LL;

  for (int cs = s0; cs < s1; cs += 32) {
    int qc = min(32, s1 - cs);
    f32x4 acc[2];
    acc[0] = (f32x4){0.f,0.f,0.f,0.f};
    acc[1] = (f32x4){0.f,0.f,0.f,0.f};

    #pragma unroll
    for (int kt = 0; kt < 2; ++kt) {
      int k0 = dq * 128 + kt * 64;
      __syncthreads();
      #pragma unroll
      for (int i = 0; i < 4; ++i) {
        int idx = i * 256 + t, r = idx >> 4, c4 = idx & 15;
        float4 v = *(const float4*)&kk_[((size_t)g * LL + r) * DD + k0 + c4 * 4];
        split_store(Kh, Kl, r, c4, v);
      }
      {
        int r = t >> 3, s = t & 7;
        uint4 vh = make_uint4(0,0,0,0);
        if (r < qc) vh = *(const uint4*)&qt[(size_t)(cs + r) * DD + k0 + s * 8];
        ((uint4*)Qs)[r * 8 + (s ^ (r & 7))] = vh;
      }
      __syncthreads();
      #pragma unroll
      for (int kk = 0; kk < 2; ++kk) {
        int sl = kk * 4 + (lane >> 4);
        int rA = wl * 16 + (lane & 15);
        short8v aH = frag(Kh, rA, sl), aL = frag(Kl, rA, sl);
        #pragma unroll
        for (int fn = 0; fn < 2; ++fn) {
          short8v bF = frag(Qs, fn * 16 + (lane & 15), sl);
          acc[fn] = __builtin_amdgcn_mfma_f32_16x16x32_bf16(aH, bF, acc[fn], 0, 0, 0);
          acc[fn] = __builtin_amdgcn_mfma_f32_16x16x32_bf16(aL, bF, acc[fn], 0, 0, 0);
        }
      }
    }
    // write partial S (row-guarded)
    {
      int cq = lane & 15, rq = lane >> 4;
      #pragma unroll
      for (int fn = 0; fn < 2; ++fn) {
        int q = fn * 16 + cq;
        if (q < qc) {
          float* row = sp + (size_t)(cs + q) * LL;
          #pragma unroll
          for (int j = 0; j < 4; ++j)
            row[wl * 16 + rq * 4 + j] = acc[fn][j];
        }
      }
    }
  }
}

// ---------------- PV: sum partials + softmax + out ----------------
// Grid 512: g = bx>>1, dh = bx&1. 256 threads = 4 waves. S_lds [q][l]-major.
__global__ __launch_bounds__(256) void k_pv2(
    const float* __restrict__ s_part, const float* __restrict__ vv_,
    const float* __restrict__ msk, const int* __restrict__ starts,
    float* __restrict__ out) {
  int g = blockIdx.x >> 1, dh = blockIdx.x & 1;
  int t = threadIdx.x, lane = t & 63, wid = t >> 6;
  int s0 = starts[g], s1 = starts[g + 1];
  if (s0 >= s1) return;

  __shared__ __align__(16) float S_lds[32][68];   // 8.7 KB
  __shared__ float bias_lds[LL];
  if (t < LL) bias_lds[t] = __expf(50.0f * (1.0f - msk[g * LL + t])) - 1.0f;

  const float* vb = vv_ + (size_t)g * LL * DD + dh * 256 + lane * 4;

  for (int cs = s0; cs < s1; cs += 32) {
    int qc = min(32, s1 - cs);
    __syncthreads();
    // sum 4 quarters + scale + bias -> S_lds[q][l]
    #pragma unroll
    for (int i = 0; i < 2; ++i) {
      int f = i * 256 + t;
      int q = f >> 4, l4 = f & 15;
      const float* p = s_part + (size_t)(cs + q) * LL + l4 * 4;
      float4 a0 = *(const float4*)p;
      float4 a1 = *(const float4*)(p + (size_t)NQ * LL);
      float4 a2 = *(const float4*)(p + (size_t)2 * NQ * LL);
      float4 a3 = *(const float4*)(p + (size_t)3 * NQ * LL);
      float4 r;
      r.x = (a0.x + a1.x + a2.x + a3.x) * SCALE - bias_lds[l4 * 4 + 0];
      r.y = (a0.y + a1.y + a2.y + a3.y) * SCALE - bias_lds[l4 * 4 + 1];
      r.z = (a0.z + a1.z + a2.z + a3.z) * SCALE - bias_lds[l4 * 4 + 2];
      r.w = (a0.w + a1.w + a2.w + a3.w) * SCALE - bias_lds[l4 * 4 + 3];
      *(float4*)&S_lds[q][l4 * 4] = r;
    }
    __syncthreads();
    // softmax per q over 64 l: 32 q x 8 lanes
    {
      int q = t >> 3, i = t & 7;
      float4 x0 = *(const float4*)&S_lds[q][i * 8];
      float4 x1 = *(const float4*)&S_lds[q][i * 8 + 4];
      float mx = fmaxf(fmaxf(fmaxf(x0.x, x0.y), fmaxf(x0.z, x0.w)),
                       fmaxf(fmaxf(x1.x, x1.y), fmaxf(x1.z, x1.w)));
      #pragma unroll
      for (int off = 1; off < 8; off <<= 1) mx = fmaxf(mx, __shfl_xor(mx, off, 8));
      float e0 = __expf(x0.x - mx), e1 = __expf(x0.y - mx);
      float e2 = __expf(x0.z - mx), e3 = __expf(x0.w - mx);
      float e4 = __expf(x1.x - mx), e5 = __expf(x1.y - mx);
      float e6 = __expf(x1.z - mx), e7 = __expf(x1.w - mx);
      float sum = ((e0 + e1) + (e2 + e3)) + ((e4 + e5) + (e6 + e7));
      #pragma unroll
      for (int off = 1; off < 8; off <<= 1) sum += __shfl_xor(sum, off, 8);
      float inv = 1.0f / sum;
      *(float4*)&S_lds[q][i * 8]     = make_float4(e0 * inv, e1 * inv, e2 * inv, e3 * inv);
      *(float4*)&S_lds[q][i * 8 + 4] = make_float4(e4 * inv, e5 * inv, e6 * inv, e7 * inv);
    }
    __syncthreads();
    // PV: wave wid -> queries wid*8..+7; lane -> d = dh*256 + lane*4..+3
    {
      float o[8][4];
      #pragma unroll
      for (int u = 0; u < 8; ++u)
        #pragma unroll
        for (int e = 0; e < 4; ++e) o[u][e] = 0.f;
      for (int l0 = 0; l0 < LL; l0 += 4) {
        float a_[8][4];
        #pragma unroll
        for (int u = 0; u < 8; ++u) {
          float4 av = *(const float4*)&S_lds[wid * 8 + u][l0];
          a_[u][0] = av.x; a_[u][1] = av.y; a_[u][2] = av.z; a_[u][3] = av.w;
        }
        #pragma unroll
        for (int e = 0; e < 4; ++e) {
          float4 vv = *(const float4*)&vb[(size_t)(l0 + e) * DD];
          #pragma unroll
          for (int u = 0; u < 8; ++u) {
            o[u][0] += a_[u][e] * vv.x;
            o[u][1] += a_[u][e] * vv.y;
            o[u][2] += a_[u][e] * vv.z;
            o[u][3] += a_[u][e] * vv.w;
          }
        }
      }
      #pragma unroll
      for (int u = 0; u < 8; ++u) {
        int q = wid * 8 + u;
        if (q < qc) {
          *(float4*)&out[(size_t)(cs + q) * DD + dh * 256 + lane * 4] =
              make_float4(o[u][0], o[u][1], o[u][2], o[u][3]);
        }
      }
    }
  }
}

extern "C" void kernel_launch(void* const* d_in, const int* in_sizes, int n_in,
                              void* d_out, int out_size, void* d_ws, size_t ws_size,
                              hipStream_t stream) {
  const float* q_in = (const float*)d_in[0];
  const float* k_in = (const float*)d_in[1];
  const float* v_in = (const float*)d_in[2];
  const float* m_in = (const float*)d_in[3];
  const int*   gid  = (const int*)d_in[4];
  const float* Wq   = (const float*)d_in[5];
  const float* bq   = (const float*)d_in[6];
  const float* Wk   = (const float*)d_in[7];
  // d_in[8] = bk: per-query constant on all scores -> cancels in softmax.
  float* out = (float*)d_out;

  // ws: w2t[1MB] | qt[4MB] | qbf[8MB] | b2 | starts | s_part[4MB]
  unsigned short* w2t = (unsigned short*)d_ws;
  unsigned short* qt  = w2t + 512 * 1024;
  unsigned short* qbf = qt + 4096 * 512;
  float* b2 = (float*)(qbf + 4096 * 1024);
  int* starts = (int*)(b2 + 512);
  float* s_part = (float*)(starts + 512);   // [4][4096][64]

  // 1) prep: w2t (0-511) + qbf (512-2559) + starts (2560) + b2 (2561-2562)
  k_prep<<<2563, 256, 0, stream>>>(q_in, gid, Wk, Wq, bq, qbf, starts, b2, w2t);
  // 2) qt = q @ W2 + b2 (single bf16 out)
  gemm_qt_mfma<<<dim3(8, 64), 256, 0, stream>>>(qbf, w2t, b2, qt);
  // 3) partial scores, 4-way d-split (1024 blocks)
  k_scores4<<<NGRP * 4, 256, 0, stream>>>(qt, k_in, starts, s_part);
  // 4) sum + softmax + PV, 2-way d-split (512 blocks)
  k_pv2<<<NGRP * 2, 256, 0, stream>>>(s_part, v_in, m_in, starts, out);
}

// Round 9
// 77.159 us; speedup vs baseline: 1.0284x; 1.0284x over previous
//
#include <hip/hip_runtime.h>

#define NQ   4096
#define NGRP 256
#define LL   64
#define DD   512

typedef __attribute__((ext_vector_type(8))) short short8v;
typedef __attribute__((ext_vector_type(4))) float f32x4;
typedef __attribute__((ext_vector_type(4))) unsigned short us4v;

#define SCALE 0.044194173824159216f

// float -> bf16 bits, round-to-nearest-even
static __device__ __forceinline__ unsigned short f2bf(float f) {
  union { float f; unsigned u; } x{f};
  unsigned r = x.u + 0x7fffu + ((x.u >> 16) & 1u);
  return (unsigned short)(r >> 16);
}
static __device__ __forceinline__ float bf2f(unsigned short h) {
  union { unsigned u; float f; } x{(unsigned)h << 16};
  return x.f;
}

// split fp32 float4 -> hi/lo bf16 into XOR-slot-swizzled LDS tile [rows][8 slots of us8]
static __device__ __forceinline__ void split_store(
    unsigned short* Hh, unsigned short* Hl, int r, int c4, float4 v) {
  int s = c4 >> 1, hf = c4 & 1;
  int base = (r * 8 + (s ^ (r & 7))) * 8 + hf * 4;
  unsigned short h0 = f2bf(v.x), h1 = f2bf(v.y), h2 = f2bf(v.z), h3 = f2bf(v.w);
  us4v hv = {h0, h1, h2, h3};
  us4v lv = {f2bf(v.x - bf2f(h0)), f2bf(v.y - bf2f(h1)),
             f2bf(v.z - bf2f(h2)), f2bf(v.w - bf2f(h3))};
  *(us4v*)(Hh + base) = hv;
  *(us4v*)(Hl + base) = lv;
}

// MFMA fragment load from swizzled LDS tile
static __device__ __forceinline__ short8v frag(const unsigned short* P, int r, int sl) {
  return *(const short8v*)(P + (r * 8 + (sl ^ (r & 7))) * 8);
}

// ---------------- merged prep ----------------
// blocks [0,128): W2T = Wk @ Wq^T via 3-term split MFMA (R7-validated 64-tile),
//                 SINGLE-bf16 output.
// blocks [128,2176): q fp32 -> bf16;  2176: starts;  2177-2178: b2 = Wk @ bq
__global__ __launch_bounds__(256) void k_prep(
    const float* __restrict__ q_in, const int* __restrict__ gid,
    const float* __restrict__ Wk, const float* __restrict__ Wq,
    const float* __restrict__ bq,
    unsigned short* __restrict__ qbf, int* __restrict__ starts,
    float* __restrict__ b2, unsigned short* __restrict__ w2t) {
  __shared__ __align__(16) unsigned short lds[4 * 64 * 64];  // 32 KB
  int b = blockIdx.x, t = threadIdx.x;
  if (b < 128) {
    unsigned short* Ah = lds;
    unsigned short* Al = lds + 4096;
    unsigned short* Bh = lds + 8192;
    unsigned short* Bl = lds + 12288;
    int lane = t & 63, wid = t >> 6;
    int wm = wid >> 1, wn = wid & 1;
    int n0 = (b & 15) * 64, m0 = (b >> 4) * 64;
    f32x4 acc[2][2];
    #pragma unroll
    for (int i = 0; i < 2; ++i)
      #pragma unroll
      for (int j = 0; j < 2; ++j) acc[i][j] = (f32x4){0.f,0.f,0.f,0.f};

    for (int k0 = 0; k0 < 512; k0 += 64) {
      __syncthreads();
      #pragma unroll
      for (int i = 0; i < 4; ++i) {
        int idx = i * 256 + t, r = idx >> 4, c4 = idx & 15;
        float4 vA = *(const float4*)&Wk[(size_t)(m0 + r) * 512 + k0 + c4 * 4];
        split_store(Ah, Al, r, c4, vA);
        float4 vB = *(const float4*)&Wq[(size_t)(n0 + r) * 512 + k0 + c4 * 4];
        split_store(Bh, Bl, r, c4, vB);
      }
      __syncthreads();
      #pragma unroll
      for (int kk = 0; kk < 2; ++kk) {
        int sl = kk * 4 + (lane >> 4);
        short8v aH[2], aL[2], bH[2], bL[2];
        #pragma unroll
        for (int fm = 0; fm < 2; ++fm) {
          int r = wm * 32 + fm * 16 + (lane & 15);
          aH[fm] = frag(Ah, r, sl); aL[fm] = frag(Al, r, sl);
        }
        #pragma unroll
        for (int fn = 0; fn < 2; ++fn) {
          int r = wn * 32 + fn * 16 + (lane & 15);
          bH[fn] = frag(Bh, r, sl); bL[fn] = frag(Bl, r, sl);
        }
        #pragma unroll
        for (int fm = 0; fm < 2; ++fm)
          #pragma unroll
          for (int fn = 0; fn < 2; ++fn) {
            acc[fm][fn] = __builtin_amdgcn_mfma_f32_16x16x32_bf16(aH[fm], bH[fn], acc[fm][fn], 0, 0, 0);
            acc[fm][fn] = __builtin_amdgcn_mfma_f32_16x16x32_bf16(aH[fm], bL[fn], acc[fm][fn], 0, 0, 0);
            acc[fm][fn] = __builtin_amdgcn_mfma_f32_16x16x32_bf16(aL[fm], bH[fn], acc[fm][fn], 0, 0, 0);
          }
      }
    }
    int cn = lane & 15, rq = lane >> 4;
    #pragma unroll
    for (int fm = 0; fm < 2; ++fm)
      #pragma unroll
      for (int fn = 0; fn < 2; ++fn)
        #pragma unroll
        for (int j = 0; j < 4; ++j) {
          int m = m0 + wm * 32 + fm * 16 + rq * 4 + j;
          int n = n0 + wn * 32 + fn * 16 + cn;
          w2t[(size_t)m * 1024 + n] = f2bf(acc[fm][fn][j]);
        }
  } else if (b < 2176) {
    int idx = (b - 128) * 256 + t;   // one uint4 (8 bf16) per thread
    const float* src = q_in + (size_t)idx * 8;
    float4 f0 = *(const float4*)src;
    float4 f1 = *(const float4*)(src + 4);
    uint4 pk;
    pk.x = (unsigned)f2bf(f0.x) | ((unsigned)f2bf(f0.y) << 16);
    pk.y = (unsigned)f2bf(f0.z) | ((unsigned)f2bf(f0.w) << 16);
    pk.z = (unsigned)f2bf(f1.x) | ((unsigned)f2bf(f1.y) << 16);
    pk.w = (unsigned)f2bf(f1.z) | ((unsigned)f2bf(f1.w) << 16);
    ((uint4*)qbf)[idx] = pk;
  } else if (b == 2176) {
    for (int g = t; g <= NGRP; g += 256) {
      int lo = 0, hi = NQ;
      while (lo < hi) { int mid = (lo + hi) >> 1; if (gid[mid] < g) lo = mid + 1; else hi = mid; }
      starts[g] = lo;
    }
  } else {
    int dd = (b - 2177) * 256 + t;
    if (dd < DD) {
      float s = 0.f;
      const float* row = Wk + (size_t)dd * DD;
      for (int j = 0; j < DD; j += 4) {
        float4 w = *(const float4*)&row[j];
        float4 bb = *(const float4*)&bq[j];
        s += w.x*bb.x + w.y*bb.y + w.z*bb.z + w.w*bb.w;
      }
      b2[dd] = s;
    }
  }
}

// ---------------- qt = q @ W2 + b2 via 1-term bf16 MFMA ----------------
// A = qbf [4096][1024], B = w2t [512][1024] (single bf16). Output single bf16.
__global__ __launch_bounds__(256) void gemm_qt_mfma(
    const unsigned short* __restrict__ qbf,
    const unsigned short* __restrict__ w2t,
    const float* __restrict__ b2,
    unsigned short* __restrict__ qt) {
  __shared__ __align__(16) unsigned short As[64 * 64];   // 8 KB
  __shared__ __align__(16) unsigned short Bs[64 * 64];   // 8 KB
  int t = threadIdx.x;
  int lane = t & 63, wid = t >> 6;
  int wm = wid >> 1, wn = wid & 1;
  int n0 = blockIdx.x * 64, m0 = blockIdx.y * 64;

  f32x4 acc[2][2];
  #pragma unroll
  for (int i = 0; i < 2; ++i)
    #pragma unroll
    for (int j = 0; j < 2; ++j) acc[i][j] = (f32x4){0.f, 0.f, 0.f, 0.f};

  for (int k0 = 0; k0 < 1024; k0 += 64) {
    __syncthreads();
    #pragma unroll
    for (int i = 0; i < 2; ++i) {
      int idx = i * 256 + t;
      int r = idx >> 3, s = idx & 7;
      int dst = r * 8 + (s ^ (r & 7));
      ((uint4*)As)[dst] = *(const uint4*)(qbf + (size_t)(m0 + r) * 1024 + k0 + s * 8);
      ((uint4*)Bs)[dst] = *(const uint4*)(w2t + (size_t)(n0 + r) * 1024 + k0 + s * 8);
    }
    __syncthreads();
    #pragma unroll
    for (int kk = 0; kk < 2; ++kk) {
      short8v aF[2], bF[2];
      int sl = kk * 4 + (lane >> 4);
      #pragma unroll
      for (int fm = 0; fm < 2; ++fm)
        aF[fm] = frag(As, wm * 32 + fm * 16 + (lane & 15), sl);
      #pragma unroll
      for (int fn = 0; fn < 2; ++fn)
        bF[fn] = frag(Bs, wn * 32 + fn * 16 + (lane & 15), sl);
      #pragma unroll
      for (int fm = 0; fm < 2; ++fm)
        #pragma unroll
        for (int fn = 0; fn < 2; ++fn)
          acc[fm][fn] = __builtin_amdgcn_mfma_f32_16x16x32_bf16(aF[fm], bF[fn], acc[fm][fn], 0, 0, 0);
    }
  }
  int cn = lane & 15, rq = lane >> 4;
  #pragma unroll
  for (int fn = 0; fn < 2; ++fn) {
    int n = n0 + wn * 32 + fn * 16 + cn;
    float bias = b2[n];
    #pragma unroll
    for (int fm = 0; fm < 2; ++fm)
      #pragma unroll
      for (int j = 0; j < 4; ++j) {
        int m = m0 + wm * 32 + fm * 16 + rq * 4 + j;
        qt[(size_t)m * 512 + n] = f2bf(acc[fm][fn][j] + bias);
      }
  }
}

// ---------------- partial scores: S_part[dq][n][l] ----------------
// Grid 1024: g = bx>>2, dq = bx&3. 256 threads = 4 waves, wave wl owns l-tile.
// K split 2-term (exact in K); Q single bf16.
__global__ __launch_bounds__(256) void k_scores4(
    const unsigned short* __restrict__ qt,
    const float* __restrict__ kk_, const int* __restrict__ starts,
    float* __restrict__ s_part) {
  int g = blockIdx.x >> 2, dq = blockIdx.x & 3;
  int t = threadIdx.x, lane = t & 63, wl = t >> 6;
  int s0 = starts[g], s1 = starts[g + 1];
  if (s0 >= s1) return;

  __shared__ __align__(16) unsigned short Kh[64*64], Kl[64*64];  // 8 KB each
  __shared__ __align__(16) unsigned short Qs[32*64];             // 4 KB

  float* sp = s_part + (size_t)dq * NQ * LL;

  for (int cs = s0; cs < s1; cs += 32) {
    int qc = min(32, s1 - cs);
    f32x4 acc[2];
    acc[0] = (f32x4){0.f,0.f,0.f,0.f};
    acc[1] = (f32x4){0.f,0.f,0.f,0.f};

    #pragma unroll
    for (int kt = 0; kt < 2; ++kt) {
      int k0 = dq * 128 + kt * 64;
      __syncthreads();
      #pragma unroll
      for (int i = 0; i < 4; ++i) {
        int idx = i * 256 + t, r = idx >> 4, c4 = idx & 15;
        float4 v = *(const float4*)&kk_[((size_t)g * LL + r) * DD + k0 + c4 * 4];
        split_store(Kh, Kl, r, c4, v);
      }
      {
        int r = t >> 3, s = t & 7;
        uint4 vh = make_uint4(0,0,0,0);
        if (r < qc) vh = *(const uint4*)&qt[(size_t)(cs + r) * DD + k0 + s * 8];
        ((uint4*)Qs)[r * 8 + (s ^ (r & 7))] = vh;
      }
      __syncthreads();
      #pragma unroll
      for (int kk = 0; kk < 2; ++kk) {
        int sl = kk * 4 + (lane >> 4);
        int rA = wl * 16 + (lane & 15);
        short8v aH = frag(Kh, rA, sl), aL = frag(Kl, rA, sl);
        #pragma unroll
        for (int fn = 0; fn < 2; ++fn) {
          short8v bF = frag(Qs, fn * 16 + (lane & 15), sl);
          acc[fn] = __builtin_amdgcn_mfma_f32_16x16x32_bf16(aH, bF, acc[fn], 0, 0, 0);
          acc[fn] = __builtin_amdgcn_mfma_f32_16x16x32_bf16(aL, bF, acc[fn], 0, 0, 0);
        }
      }
    }
    // write partial S (row-guarded)
    {
      int cq = lane & 15, rq = lane >> 4;
      #pragma unroll
      for (int fn = 0; fn < 2; ++fn) {
        int q = fn * 16 + cq;
        if (q < qc) {
          float* row = sp + (size_t)(cs + q) * LL;
          #pragma unroll
          for (int j = 0; j < 4; ++j)
            row[wl * 16 + rq * 4 + j] = acc[fn][j];
        }
      }
    }
  }
}

// ---------------- PV: sum partials + softmax + out ----------------
// Grid 512: g = bx>>1, dh = bx&1. 256 threads = 4 waves. S_lds [q][l]-major.
__global__ __launch_bounds__(256) void k_pv2(
    const float* __restrict__ s_part, const float* __restrict__ vv_,
    const float* __restrict__ msk, const int* __restrict__ starts,
    float* __restrict__ out) {
  int g = blockIdx.x >> 1, dh = blockIdx.x & 1;
  int t = threadIdx.x, lane = t & 63, wid = t >> 6;
  int s0 = starts[g], s1 = starts[g + 1];
  if (s0 >= s1) return;

  __shared__ __align__(16) float S_lds[32][68];   // 8.7 KB
  __shared__ float bias_lds[LL];
  if (t < LL) bias_lds[t] = __expf(50.0f * (1.0f - msk[g * LL + t])) - 1.0f;

  const float* vb = vv_ + (size_t)g * LL * DD + dh * 256 + lane * 4;

  for (int cs = s0; cs < s1; cs += 32) {
    int qc = min(32, s1 - cs);
    __syncthreads();
    // sum 4 quarters + scale + bias -> S_lds[q][l]
    #pragma unroll
    for (int i = 0; i < 2; ++i) {
      int f = i * 256 + t;
      int q = f >> 4, l4 = f & 15;
      const float* p = s_part + (size_t)(cs + q) * LL + l4 * 4;
      float4 a0 = *(const float4*)p;
      float4 a1 = *(const float4*)(p + (size_t)NQ * LL);
      float4 a2 = *(const float4*)(p + (size_t)2 * NQ * LL);
      float4 a3 = *(const float4*)(p + (size_t)3 * NQ * LL);
      float4 r;
      r.x = (a0.x + a1.x + a2.x + a3.x) * SCALE - bias_lds[l4 * 4 + 0];
      r.y = (a0.y + a1.y + a2.y + a3.y) * SCALE - bias_lds[l4 * 4 + 1];
      r.z = (a0.z + a1.z + a2.z + a3.z) * SCALE - bias_lds[l4 * 4 + 2];
      r.w = (a0.w + a1.w + a2.w + a3.w) * SCALE - bias_lds[l4 * 4 + 3];
      *(float4*)&S_lds[q][l4 * 4] = r;
    }
    __syncthreads();
    // softmax per q over 64 l: 32 q x 8 lanes
    {
      int q = t >> 3, i = t & 7;
      float4 x0 = *(const float4*)&S_lds[q][i * 8];
      float4 x1 = *(const float4*)&S_lds[q][i * 8 + 4];
      float mx = fmaxf(fmaxf(fmaxf(x0.x, x0.y), fmaxf(x0.z, x0.w)),
                       fmaxf(fmaxf(x1.x, x1.y), fmaxf(x1.z, x1.w)));
      #pragma unroll
      for (int off = 1; off < 8; off <<= 1) mx = fmaxf(mx, __shfl_xor(mx, off, 8));
      float e0 = __expf(x0.x - mx), e1 = __expf(x0.y - mx);
      float e2 = __expf(x0.z - mx), e3 = __expf(x0.w - mx);
      float e4 = __expf(x1.x - mx), e5 = __expf(x1.y - mx);
      float e6 = __expf(x1.z - mx), e7 = __expf(x1.w - mx);
      float sum = ((e0 + e1) + (e2 + e3)) + ((e4 + e5) + (e6 + e7));
      #pragma unroll
      for (int off = 1; off < 8; off <<= 1) sum += __shfl_xor(sum, off, 8);
      float inv = 1.0f / sum;
      *(float4*)&S_lds[q][i * 8]     = make_float4(e0 * inv, e1 * inv, e2 * inv, e3 * inv);
      *(float4*)&S_lds[q][i * 8 + 4] = make_float4(e4 * inv, e5 * inv, e6 * inv, e7 * inv);
    }
    __syncthreads();
    // PV: wave wid -> queries wid*8..+7; lane -> d = dh*256 + lane*4..+3
    {
      float o[8][4];
      #pragma unroll
      for (int u = 0; u < 8; ++u)
        #pragma unroll
        for (int e = 0; e < 4; ++e) o[u][e] = 0.f;
      for (int l0 = 0; l0 < LL; l0 += 4) {
        float a_[8][4];
        #pragma unroll
        for (int u = 0; u < 8; ++u) {
          float4 av = *(const float4*)&S_lds[wid * 8 + u][l0];
          a_[u][0] = av.x; a_[u][1] = av.y; a_[u][2] = av.z; a_[u][3] = av.w;
        }
        #pragma unroll
        for (int e = 0; e < 4; ++e) {
          float4 vv = *(const float4*)&vb[(size_t)(l0 + e) * DD];
          #pragma unroll
          for (int u = 0; u < 8; ++u) {
            o[u][0] += a_[u][e] * vv.x;
            o[u][1] += a_[u][e] * vv.y;
            o[u][2] += a_[u][e] * vv.z;
            o[u][3] += a_[u][e] * vv.w;
          }
        }
      }
      #pragma unroll
      for (int u = 0; u < 8; ++u) {
        int q = wid * 8 + u;
        if (q < qc) {
          *(float4*)&out[(size_t)(cs + q) * DD + dh * 256 + lane * 4] =
              make_float4(o[u][0], o[u][1], o[u][2], o[u][3]);
        }
      }
    }
  }
}

extern "C" void kernel_launch(void* const* d_in, const int* in_sizes, int n_in,
                              void* d_out, int out_size, void* d_ws, size_t ws_size,
                              hipStream_t stream) {
  const float* q_in = (const float*)d_in[0];
  const float* k_in = (const float*)d_in[1];
  const float* v_in = (const float*)d_in[2];
  const float* m_in = (const float*)d_in[3];
  const int*   gid  = (const int*)d_in[4];
  const float* Wq   = (const float*)d_in[5];
  const float* bq   = (const float*)d_in[6];
  const float* Wk   = (const float*)d_in[7];
  // d_in[8] = bk: per-query constant on all scores -> cancels in softmax.
  float* out = (float*)d_out;

  // ws: w2t[1MB] | qt[4MB] | qbf[8MB] | b2 | starts | s_part[4MB]
  unsigned short* w2t = (unsigned short*)d_ws;
  unsigned short* qt  = w2t + 512 * 1024;
  unsigned short* qbf = qt + 4096 * 512;
  float* b2 = (float*)(qbf + 4096 * 1024);
  int* starts = (int*)(b2 + 512);
  float* s_part = (float*)(starts + 512);   // [4][4096][64]

  // 1) prep: w2t (0-127, R7 64-tile) + qbf (128-2175) + starts (2176) + b2 (2177-2178)
  k_prep<<<2179, 256, 0, stream>>>(q_in, gid, Wk, Wq, bq, qbf, starts, b2, w2t);
  // 2) qt = q @ W2 + b2 (1-term, single bf16 out)
  gemm_qt_mfma<<<dim3(8, 64), 256, 0, stream>>>(qbf, w2t, b2, qt);
  // 3) partial scores, 4-way d-split (1024 blocks)
  k_scores4<<<NGRP * 4, 256, 0, stream>>>(qt, k_in, starts, s_part);
  // 4) sum + softmax + PV, 2-way d-split (512 blocks)
  k_pv2<<<NGRP * 2, 256, 0, stream>>>(s_part, v_in, m_in, starts, out);
}